// Round 11
// baseline (480.768 us; speedup 1.0000x reference)
//
#include <hip/hip_runtime.h>
#include <hip/hip_bf16.h>

#define C 128
#define NBKT 128
#define BCAP 8192

typedef __bf16 bf16x8 __attribute__((ext_vector_type(8)));
typedef float floatx4 __attribute__((ext_vector_type(4)));

// ---- manual bf16 helpers ----
__device__ __forceinline__ unsigned short f2bf(float f) {
    unsigned u = __float_as_uint(f);
    unsigned r = (u + 0x7FFFu + ((u >> 16) & 1u)) >> 16;
    return (unsigned short)r;
}
__device__ __forceinline__ float bflo(unsigned v) { return __uint_as_float(v << 16); }
__device__ __forceinline__ float bfhi(unsigned v) { return __uint_as_float(v & 0xFFFF0000u); }
__device__ __forceinline__ unsigned packbf(float lo, float hi) {
    return (unsigned)f2bf(lo) | ((unsigned)f2bf(hi) << 16);
}

// ---- dtype-flexible accessors ----
__device__ __forceinline__ int g_idx(const void* p, long long i, int is64) {
    if (is64) return (int)((const long long*)p)[i];
    return ((const int*)p)[i];
}
__device__ __forceinline__ float g_flt(const void* p, long long i, int isf32) {
    if (isf32) return ((const float*)p)[i];
    return __uint_as_float(((unsigned)((const unsigned short*)p)[i]) << 16);
}

// -------- phase A: bucket edges into 128 row-ranges (is64 detected inline) --------
__global__ void k_bucketA(const void* edge, int E, int rpb,
                          unsigned* __restrict__ bucketbuf, int* __restrict__ bucketcnt) {
    __shared__ int lcnt[NBKT];
    __shared__ int lbase[NBKT];
    __shared__ int sflag;
    int t = threadIdx.x;
    if (t < 64) {
        const unsigned* wrd = (const unsigned*)edge;
        int predA = (t < 32) ? (wrd[2 * t + 1] == 0u) : 1;
        unsigned long long mA = __ballot(predA);
        if (t == 0) sflag = (mA == ~0ull) ? 1 : 0;
    }
    __syncthreads();
    int is64 = sflag;
    const int PER = 8;
    int chunkSz = blockDim.x * PER;
    long long stride = (long long)gridDim.x * chunkSz;
    for (long long base = (long long)blockIdx.x * chunkSz; base < E; base += stride) {
        if (t < NBKT) lcnt[t] = 0;
        __syncthreads();
        int bkt[PER], rank[PER];
        unsigned enc[PER];
        long long e0 = base + (long long)t * PER;
        int rr[PER], cc[PER];
        if (e0 + PER <= E) {
            if (is64) {
                const long long* pr = (const long long*)edge + e0;
                const long long* pc = (const long long*)edge + E + e0;
#pragma unroll
                for (int j = 0; j < PER; j += 2) {
                    longlong2 vr = *(const longlong2*)(pr + j);
                    longlong2 vc = *(const longlong2*)(pc + j);
                    rr[j] = (int)vr.x; rr[j + 1] = (int)vr.y;
                    cc[j] = (int)vc.x; cc[j + 1] = (int)vc.y;
                }
            } else {
                const int* pr = (const int*)edge + e0;
                const int* pc = (const int*)edge + E + e0;
#pragma unroll
                for (int j = 0; j < PER; j += 4) {
                    int4 vr = *(const int4*)(pr + j);
                    int4 vc = *(const int4*)(pc + j);
                    rr[j] = vr.x; rr[j + 1] = vr.y; rr[j + 2] = vr.z; rr[j + 3] = vr.w;
                    cc[j] = vc.x; cc[j + 1] = vc.y; cc[j + 2] = vc.z; cc[j + 3] = vc.w;
                }
            }
#pragma unroll
            for (int j = 0; j < PER; ++j) {
                int b = rr[j] / rpb;
                bkt[j] = b;
                enc[j] = ((unsigned)(rr[j] - b * rpb) << 16) | (unsigned)(cc[j] & 0xFFFF);
                rank[j] = atomicAdd(&lcnt[b], 1);
            }
        } else {
#pragma unroll
            for (int j = 0; j < PER; ++j) {
                long long e = e0 + j;
                if (e < E) {
                    int r = g_idx(edge, e, is64);
                    int c = g_idx(edge, (long long)E + e, is64);
                    int b = r / rpb;
                    bkt[j] = b;
                    enc[j] = ((unsigned)(r - b * rpb) << 16) | (unsigned)(c & 0xFFFF);
                    rank[j] = atomicAdd(&lcnt[b], 1);
                } else bkt[j] = -1;
            }
        }
        __syncthreads();
        if (t < NBKT) lbase[t] = atomicAdd(&bucketcnt[t], lcnt[t]);
        __syncthreads();
#pragma unroll
        for (int j = 0; j < PER; ++j) {
            if (bkt[j] >= 0) {
                int pos = lbase[bkt[j]] + rank[j];
                if (pos < BCAP)
                    bucketbuf[(size_t)bkt[j] * BCAP + pos] = enc[j];
            }
        }
    }
}

// -------- phase B: block b owns bucket b; also emits degree array + degree histogram ----
__global__ __launch_bounds__(512) void k_bsort(
        const unsigned* __restrict__ bucketbuf, const int* __restrict__ bucketcnt,
        int* __restrict__ rowptr, float* __restrict__ dinv, float* __restrict__ di2,
        float* __restrict__ rdinv, unsigned short* __restrict__ cols16,
        int* __restrict__ deg, int* __restrict__ dh, int N, int rpb) {
    __shared__ int hist[512];
    int b = blockIdx.x;
    int t = threadIdx.x;
    int base = 0, cnt = 0, total = 0;
    for (int i = 0; i < NBKT; ++i) {
        int v = bucketcnt[i];
        if (v > BCAP) v = BCAP;
        if (i < b) base += v;
        if (i == b) cnt = v;
        total += v;
    }
    int r0 = b * rpb;
    int rows = N - r0;
    if (rows > rpb) rows = rpb;
    if (rows < 0) rows = 0;

    hist[t] = 0;
    __syncthreads();
    const unsigned* buf = bucketbuf + (size_t)b * BCAP;
    for (int i = t; i < cnt; i += 512) atomicAdd(&hist[buf[i] >> 16], 1);
    __syncthreads();
    int v = hist[t];
    __syncthreads();
    for (int off = 1; off < 512; off <<= 1) {
        int x = (t >= off) ? hist[t - off] : 0;
        __syncthreads();
        hist[t] += x;
        __syncthreads();
    }
    int excl = hist[t] - v;
    if (t < rows) {
        int r = r0 + t;
        rowptr[r] = base + excl;
        deg[r] = v;
        atomicAdd(&dh[v > 1023 ? 1023 : v], 1);
        float fd = (float)v;
        float dv = (v > 0) ? rsqrtf(fd) : 0.0f;
        dinv[r] = dv;
        di2[r] = dv * dv;
        rdinv[r] = (v > 0) ? sqrtf(fd) : 0.0f;
    }
    if (b == NBKT - 1 && t == 0) rowptr[N] = total;
    __syncthreads();
    hist[t] = base + excl;  // global cursor per owned row
    __syncthreads();
    for (int i = t; i < cnt; i += 512) {
        unsigned u = buf[i];
        int pos = atomicAdd(&hist[u >> 16], 1);
        cols16[pos] = (unsigned short)(u & 0xFFFF);
    }
}

// -------- exclusive prefix over 1024-bin degree histogram --------
__global__ __launch_bounds__(1024) void k_dscan(const int* __restrict__ dh,
                                                int* __restrict__ dcur) {
    __shared__ int s[1024];
    int t = threadIdx.x;
    int v = dh[t];
    s[t] = v;
    __syncthreads();
    for (int off = 1; off < 1024; off <<= 1) {
        int x = (t >= off) ? s[t - off] : 0;
        __syncthreads();
        s[t] += x;
        __syncthreads();
    }
    dcur[t] = s[t] - v;
}

// -------- place nodes into degree-sorted order --------
__global__ void k_place(const int* __restrict__ deg, int N,
                        int* __restrict__ dcur, int* __restrict__ order) {
    int n = blockIdx.x * blockDim.x + threadIdx.x;
    if (n < N) {
        int d = deg[n]; if (d > 1023) d = 1023;
        int pos = atomicAdd(&dcur[d], 1);
        order[pos] = n;
    }
}

// -------- init + prep fused: h0/g0 (slice-major), W1T transpose, biases, n_id marking ----
__global__ void k_initprep(const void* emb, const float* __restrict__ dinv,
                           unsigned* __restrict__ h0, unsigned* __restrict__ g0,
                           unsigned* __restrict__ g1, unsigned* __restrict__ g2,
                           int n2, int SST,
                           const void* w1, const void* b1, const void* w2, const void* b2,
                           unsigned short* __restrict__ w1t, float* __restrict__ b1f,
                           float* __restrict__ w2f, float* __restrict__ b2f,
                           const void* n_id, int nids, unsigned char* __restrict__ mark) {
    __shared__ int sf32, sid;
    int t = threadIdx.x;
    if (t < 64) {
        const unsigned short* h = (const unsigned short*)emb;
        int ex = (h[2 * t] >> 7) & 0xFF;
        unsigned long long mP = __ballot(ex >= 0x6C && ex <= 0x7F);
        const unsigned* nw = (const unsigned*)n_id;
        int predB = (t < 32) ? (nw[2 * t + 1] == 0u) : 1;
        unsigned long long mB = __ballot(predB);
        if (t == 0) {
            sf32 = (__popcll(mP) < 32) ? 1 : 0;
            sid = (mB == ~0ull) ? 1 : 0;
        }
    }
    __syncthreads();
    int f32 = sf32, id64 = sid;
    int i = blockIdx.x * blockDim.x + t;
    if (i < n2) {
        float lo = g_flt(emb, 2LL * i, f32);
        float hi = g_flt(emb, 2LL * i + 1, f32);
        int n = i >> 6, w = i & 63;
        size_t o = (size_t)(w >> 5) * SST + (size_t)n * 32 + (w & 31);
        h0[o] = packbf(lo, hi);
        float dv = dinv[n];
        g0[o] = packbf(lo * dv, hi * dv);
    }
    if (i < nids) mark[g_idx(n_id, i, id64)] = 1;  // rows needed by the head
    if (i < 256 * 128) {
        int k = i >> 7, n = i & 127;
        w1t[n * 256 + k] = f2bf(g_flt(w1, i, f32));
    }
    if (i < 128) {
        b1f[i] = g_flt(b1, i, f32);
        w2f[i] = g_flt(w2, i, f32);
    }
    if (i == 0) b2f[0] = g_flt(b2, 0, f32);
    if (i < 64) {  // zero sentinel row N (both slices) of g0,g1,g2
        int s = i >> 5, w = i & 31;
        size_t o = (size_t)s * SST + (size_t)(n2 >> 6) * 32 + w;
        g0[o] = 0u; g1[o] = 0u; g2[o] = 0u;
    }
}

// -------- compact marked nodes from the degree-sorted order (keeps degree grouping) ----
__global__ __launch_bounds__(256) void k_compact(const unsigned char* __restrict__ mark,
                                                 const int* __restrict__ order, int N,
                                                 int* __restrict__ cnt, int* __restrict__ clist) {
    __shared__ int wbase[4];
    int i = blockIdx.x * blockDim.x + threadIdx.x;
    int n = (i < N) ? order[i] : -1;
    int m = (n >= 0) ? (mark[n] ? 1 : 0) : 0;
    int lane = threadIdx.x & 63, wave = threadIdx.x >> 6;
    unsigned long long bal = __ballot(m);
    int rank = __popcll(bal & ((1ull << lane) - 1ull));
    if (lane == 0) wbase[wave] = __popcll(bal);
    __syncthreads();
    if (threadIdx.x == 0) {
        int tot = wbase[0] + wbase[1] + wbase[2] + wbase[3];
        int b0 = atomicAdd(cnt, tot);
        int acc = b0;
#pragma unroll
        for (int w = 0; w < 4; ++w) { int c = wbase[w]; wbase[w] = acc; acc += c; }
    }
    __syncthreads();
    if (m) clist[wbase[wave] + rank] = n;
}

// -------- propagation (2-slice, 8 neighbors/trip, degree-sorted wave scheduling) --------
// slice pinned to an XCD half: slice = (blockIdx&7)>>2.
__global__ void k_layer(const int* __restrict__ rowptr, const unsigned short* __restrict__ cols16,
                        const int* __restrict__ order,
                        const uint4* __restrict__ gin, uint4* __restrict__ gout,
                        const float* __restrict__ di2, int N, int SSTU4) {
    int b = blockIdx.x;
    int slice = (b >> 2) & 1;
    int tile = ((b >> 3) << 2) | (b & 3);
    int pos = tile * 32 + (threadIdx.x >> 3);
    if (pos >= N) return;
    int node = order[pos];
    int l8 = threadIdx.x & 7;
    const uint4* gs = gin + (size_t)slice * SSTU4;
    int p = rowptr[node];
    int end = rowptr[node + 1];
    float a0 = 0.f, a1 = 0.f, a2 = 0.f, a3 = 0.f;
    float a4 = 0.f, a5 = 0.f, a6 = 0.f, a7 = 0.f;
    for (int base = p; base < end; base += 8) {
        int c[8];
#pragma unroll
        for (int j = 0; j < 8; ++j) {
            int idx = base + j;
            int cv = cols16[idx];
            c[j] = (idx < end) ? cv : N;
        }
#pragma unroll
        for (int j = 0; j < 8; ++j) {
            uint4 v = gs[(size_t)c[j] * 8 + l8];
            a0 += bflo(v.x); a1 += bfhi(v.x);
            a2 += bflo(v.y); a3 += bfhi(v.y);
            a4 += bflo(v.z); a5 += bfhi(v.z);
            a6 += bflo(v.w); a7 += bfhi(v.w);
        }
    }
    float s = di2[node];
    uint4 o;
    o.x = packbf(a0 * s, a1 * s);
    o.y = packbf(a2 * s, a3 * s);
    o.z = packbf(a4 * s, a5 * s);
    o.w = packbf(a6 * s, a7 * s);
    gout[(size_t)slice * SSTU4 + (size_t)node * 8 + l8] = o;
}

// -------- layer 3: dense waves over compacted (degree-grouped) list; fused finalize ----
__global__ void k_layer3(const int* __restrict__ rowptr, const unsigned short* __restrict__ cols16,
                         const uint4* __restrict__ gin /*g2*/, const uint4* __restrict__ h0,
                         const uint4* __restrict__ g1, uint4* __restrict__ fin,
                         const float* __restrict__ di2, const float* __restrict__ rdinv,
                         const int* __restrict__ cnt, const int* __restrict__ clist,
                         int N, int SSTU4, int TILES_PER) {
    int b = blockIdx.x;
    int slice = (b >> 2) & 1;
    int tile = ((b >> 3) << 2) | (b & 3);
    int nsub = threadIdx.x >> 3;
    int l8 = threadIdx.x & 7;
    int cntv = *cnt;
    size_t sb = (size_t)slice * SSTU4;
    const uint4* gs = gin + sb;
    for (int tl = tile; tl * 32 < cntv; tl += TILES_PER) {
        int li = tl * 32 + nsub;
        if (li < cntv) {
            int node = clist[li];
            int p = rowptr[node], end = rowptr[node + 1];
            float a0 = 0.f, a1 = 0.f, a2 = 0.f, a3 = 0.f;
            float a4 = 0.f, a5 = 0.f, a6 = 0.f, a7 = 0.f;
            for (int base = p; base < end; base += 8) {
                int c[8];
#pragma unroll
                for (int j = 0; j < 8; ++j) {
                    int idx = base + j;
                    int cv = cols16[idx];
                    c[j] = (idx < end) ? cv : N;
                }
#pragma unroll
                for (int j = 0; j < 8; ++j) {
                    uint4 v = gs[(size_t)c[j] * 8 + l8];
                    a0 += bflo(v.x); a1 += bfhi(v.x);
                    a2 += bflo(v.y); a3 += bfhi(v.y);
                    a4 += bflo(v.z); a5 += bfhi(v.z);
                    a6 += bflo(v.w); a7 += bfhi(v.w);
                }
            }
            float s = di2[node];
            float rd = rdinv[node];
            size_t ro = (size_t)node * 8 + l8;
            uint4 x0 = h0[sb + ro];
            uint4 x1 = g1[sb + ro];
            uint4 x2 = gs[ro];
            uint4 o;
            o.x = packbf(0.25f * (bflo(x0.x) + rd * (bflo(x1.x) + bflo(x2.x) + s * a0)),
                         0.25f * (bfhi(x0.x) + rd * (bfhi(x1.x) + bfhi(x2.x) + s * a1)));
            o.y = packbf(0.25f * (bflo(x0.y) + rd * (bflo(x1.y) + bflo(x2.y) + s * a2)),
                         0.25f * (bfhi(x0.y) + rd * (bfhi(x1.y) + bfhi(x2.y) + s * a3)));
            o.z = packbf(0.25f * (bflo(x0.z) + rd * (bflo(x1.z) + bflo(x2.z) + s * a4)),
                         0.25f * (bfhi(x0.z) + rd * (bfhi(x1.z) + bfhi(x2.z) + s * a5)));
            o.w = packbf(0.25f * (bflo(x0.w) + rd * (bflo(x1.w) + bflo(x2.w) + s * a6)),
                         0.25f * (bfhi(x0.w) + rd * (bfhi(x1.w) + bfhi(x2.w) + s * a7)));
            fin[(size_t)node * 16 + slice * 8 + l8] = o;
        }
    }
}

// -------- MFMA head (fin node-major, uint4 staging; id64 detected inline) --------
__global__ void k_head(const uint4* __restrict__ fin, const void* n_id,
                       const unsigned short* __restrict__ w1t,
                       const float* __restrict__ b1f, const float* __restrict__ w2f,
                       const float* __restrict__ b2f,
                       float* __restrict__ out, int B, int NEG) {
    __shared__ unsigned short z[64][264];
    __shared__ int sid;
    int t = threadIdx.x;
    if (t < 64) {
        const unsigned* nw = (const unsigned*)n_id;
        int predB = (t < 32) ? (nw[2 * t + 1] == 0u) : 1;
        unsigned long long mB = __ballot(predB);
        if (t == 0) sid = (mB == ~0ull) ? 1 : 0;
    }
    __syncthreads();
    int id64 = sid;
    int mbase = blockIdx.x * 64;

#pragma unroll
    for (int i = 0; i < 8; ++i) {
        int flat = i * 256 + t;        // 0..2047
        int m = flat >> 5;             // 0..63
        int q = flat & 31;             // uint4 slot within z row
        int gm = mbase + m;
        int r;
        if (gm < B) {
            r = (q < 16) ? g_idx(n_id, gm, id64) : g_idx(n_id, B + gm, id64);
        } else {
            int j = gm - B;
            r = (q < 16) ? g_idx(n_id, j / NEG, id64) : g_idx(n_id, 2 * B + j, id64);
        }
        uint4 v = fin[(size_t)r * 16 + (q & 15)];
        *(uint4*)((char*)&z[m][0] + q * 16) = v;
    }
    __syncthreads();

    int wave = t >> 6, lane = t & 63;
    int quad = lane >> 4, l16 = lane & 15;

    floatx4 acc[8] = {};
    bf16x8 a[8];
    const unsigned short* zrow = &z[wave * 16 + l16][0];
#pragma unroll
    for (int ks = 0; ks < 8; ++ks)
        a[ks] = *(const bf16x8*)(zrow + ks * 32 + quad * 8);

#pragma unroll
    for (int ks = 0; ks < 8; ++ks) {
#pragma unroll
        for (int nt = 0; nt < 8; ++nt) {
            bf16x8 b = *(const bf16x8*)(w1t + (nt * 16 + l16) * 256 + ks * 32 + quad * 8);
            acc[nt] = __builtin_amdgcn_mfma_f32_16x16x32_bf16(a[ks], b, acc[nt], 0, 0, 0);
        }
    }

    float s0 = 0.f, s1 = 0.f, s2 = 0.f, s3 = 0.f;
#pragma unroll
    for (int nt = 0; nt < 8; ++nt) {
        int col = nt * 16 + l16;
        float bb = b1f[col], ww = w2f[col];
        float v0 = acc[nt][0] + bb; v0 = (v0 > 0.f) ? v0 : 0.2f * v0; s0 += v0 * ww;
        float v1 = acc[nt][1] + bb; v1 = (v1 > 0.f) ? v1 : 0.2f * v1; s1 += v1 * ww;
        float v2 = acc[nt][2] + bb; v2 = (v2 > 0.f) ? v2 : 0.2f * v2; s2 += v2 * ww;
        float v3 = acc[nt][3] + bb; v3 = (v3 > 0.f) ? v3 : 0.2f * v3; s3 += v3 * ww;
    }
#pragma unroll
    for (int off = 1; off <= 8; off <<= 1) {
        s0 += __shfl_xor(s0, off, 64);
        s1 += __shfl_xor(s1, off, 64);
        s2 += __shfl_xor(s2, off, 64);
        s3 += __shfl_xor(s3, off, 64);
    }
    if (l16 == 0) {
        int rowbase = mbase + wave * 16 + quad * 4;
        float bb2 = b2f[0];
        out[rowbase + 0] = s0 + bb2;
        out[rowbase + 1] = s1 + bb2;
        out[rowbase + 2] = s2 + bb2;
        out[rowbase + 3] = s3 + bb2;
    }
}

extern "C" void kernel_launch(void* const* d_in, const int* in_sizes, int n_in,
                              void* d_out, int out_size, void* d_ws, size_t ws_size,
                              hipStream_t stream) {
    const void* edge_index = d_in[1];
    const void* n_id       = d_in[3];
    const void* id_embed   = d_in[5];
    const void* w1 = d_in[6];
    const void* b1 = d_in[7];
    const void* w2 = d_in[8];
    const void* b2 = d_in[9];
    float* out = (float*)d_out;

    const int E  = in_sizes[1] / 2;
    const int N  = in_sizes[5] / C;
    const int NEG = 5;
    const int B  = in_sizes[3] / (2 + NEG);
    const int nids = (2 + NEG) * B;      // 28672
    const int n_out_rows = B + B * NEG;  // 24576
    const int SST = (N + 1) * 32;        // slice stride in u32 (2 slices)
    const int SSTU4 = (N + 1) * 8;       // slice stride in uint4
    const int NB = 2 * SST;              // u32 per slice-major buffer
    const int rpb = (N + NBKT - 1) / NBKT;  // 391 (<=512)

    size_t off = 0;
    auto alloc = [&](size_t nf) {
        char* p = (char*)d_ws + off * 4;
        off += (nf + 255) & ~(size_t)255;
        return p;
    };
    // zero-init region: bucketcnt(+ccnt) | mark | dh | dcur  (contiguous)
    int*   bucketcnt = (int*)alloc(NBKT);       // padded to 1024B; [128] = compact counter
    unsigned char* mark = (unsigned char*)alloc((N + 3) / 4);
    int*   dh        = (int*)alloc(1024);
    int*   dcur      = (int*)alloc(1024);
    // non-zeroed:
    int*   deg       = (int*)alloc(N);
    int*   order     = (int*)alloc(N);
    int*   clist     = (int*)alloc(N);
    float* dinv      = (float*)alloc(N + 1);
    float* di2       = (float*)alloc(N);
    float* rdinv     = (float*)alloc(N);
    int*   rowptr    = (int*)alloc(N + 1);
    unsigned short* cols16 = (unsigned short*)alloc(((size_t)E + 16 + 1) / 2);
    unsigned* bucketbuf = (unsigned*)alloc((size_t)NBKT * BCAP);
    unsigned* h0     = (unsigned*)alloc(NB);
    unsigned* g0     = (unsigned*)alloc(NB);
    unsigned* g1     = (unsigned*)alloc(NB);
    unsigned* g2     = (unsigned*)alloc(NB);
    unsigned* fin    = (unsigned*)alloc((size_t)N * 64);
    unsigned short* w1t = (unsigned short*)alloc(256 * 128 / 2);
    float* b1f       = (float*)alloc(C);
    float* w2f       = (float*)alloc(C);
    float* b2f       = (float*)alloc(8);
    int*   ccnt      = bucketcnt + 128;  // inside padded region, covered by memset

    const int BS = 256;
    size_t zlen = (size_t)((char*)deg - (char*)bucketcnt);
    hipMemsetAsync(bucketcnt, 0, zlen, stream);

    const int gridA = (E + BS * 8 - 1) / (BS * 8);
    k_bucketA<<<gridA, BS, 0, stream>>>(edge_index, E, rpb, bucketbuf, bucketcnt);
    k_bsort<<<NBKT, 512, 0, stream>>>(bucketbuf, bucketcnt, rowptr, dinv, di2, rdinv,
                                      cols16, deg, dh, N, rpb);
    k_dscan<<<1, 1024, 0, stream>>>(dh, dcur);
    k_place<<<(N + BS - 1) / BS, BS, 0, stream>>>(deg, N, dcur, order);
    k_initprep<<<(N * 64 + BS - 1) / BS, BS, 0, stream>>>(
        id_embed, dinv, h0, g0, g1, g2, N * 64, SST, w1, b1, w2, b2,
        w1t, b1f, w2f, b2f, n_id, nids, mark);
    k_compact<<<(N + BS - 1) / BS, BS, 0, stream>>>(mark, order, N, ccnt, clist);

    // layers: slice = (blockIdx&7)>>2, tile = ((b>>3)<<2)|(b&3); grid multiple of 8
    const int tiles = (N + 31) / 32;
    const int layer_grid = 8 * ((tiles + 3) / 4);
    const int TILES_PER = 4 * ((tiles + 3) / 4);
    k_layer<<<layer_grid, BS, 0, stream>>>(rowptr, cols16, order, (const uint4*)g0,
                                           (uint4*)g1, di2, N, SSTU4);
    k_layer<<<layer_grid, BS, 0, stream>>>(rowptr, cols16, order, (const uint4*)g1,
                                           (uint4*)g2, di2, N, SSTU4);
    k_layer3<<<layer_grid, BS, 0, stream>>>(rowptr, cols16, (const uint4*)g2, (const uint4*)h0,
                                            (const uint4*)g1, (uint4*)fin, di2, rdinv,
                                            ccnt, clist, N, SSTU4, TILES_PER);

    k_head<<<n_out_rows / 64, BS, 0, stream>>>((const uint4*)fin, n_id, w1t, b1f, w2f, b2f,
                                               out, B, NEG);
}

// Round 12
// 209.115 us; speedup vs baseline: 2.2991x; 2.2991x over previous
//
#include <hip/hip_runtime.h>
#include <hip/hip_bf16.h>

#define C 128
#define NBKT 256
#define BCAP 8192

typedef __bf16 bf16x8 __attribute__((ext_vector_type(8)));
typedef float floatx4 __attribute__((ext_vector_type(4)));

// ---- manual bf16 helpers ----
__device__ __forceinline__ unsigned short f2bf(float f) {
    unsigned u = __float_as_uint(f);
    unsigned r = (u + 0x7FFFu + ((u >> 16) & 1u)) >> 16;
    return (unsigned short)r;
}
__device__ __forceinline__ float bflo(unsigned v) { return __uint_as_float(v << 16); }
__device__ __forceinline__ float bfhi(unsigned v) { return __uint_as_float(v & 0xFFFF0000u); }
__device__ __forceinline__ unsigned packbf(float lo, float hi) {
    return (unsigned)f2bf(lo) | ((unsigned)f2bf(hi) << 16);
}

// ---- dtype-flexible accessors ----
__device__ __forceinline__ int g_idx(const void* p, long long i, int is64) {
    if (is64) return (int)((const long long*)p)[i];
    return ((const int*)p)[i];
}
__device__ __forceinline__ float g_flt(const void* p, long long i, int isf32) {
    if (isf32) return ((const float*)p)[i];
    return __uint_as_float(((unsigned)((const unsigned short*)p)[i]) << 16);
}

// -------- phase A: bucket edges into 256 row-ranges (is64 detected inline) --------
__global__ void k_bucketA(const void* edge, int E, int rpb,
                          unsigned* __restrict__ bucketbuf, int* __restrict__ bucketcnt) {
    __shared__ int lcnt[NBKT];
    __shared__ int lbase[NBKT];
    __shared__ int sflag;
    int t = threadIdx.x;
    if (t < 64) {
        const unsigned* wrd = (const unsigned*)edge;
        int predA = (t < 32) ? (wrd[2 * t + 1] == 0u) : 1;
        unsigned long long mA = __ballot(predA);
        if (t == 0) sflag = (mA == ~0ull) ? 1 : 0;
    }
    __syncthreads();
    int is64 = sflag;
    const int PER = 8;
    int chunkSz = blockDim.x * PER;
    long long stride = (long long)gridDim.x * chunkSz;
    for (long long base = (long long)blockIdx.x * chunkSz; base < E; base += stride) {
        if (t < NBKT) lcnt[t] = 0;
        __syncthreads();
        int bkt[PER], rank[PER];
        unsigned enc[PER];
        long long e0 = base + (long long)t * PER;
        int rr[PER], cc[PER];
        if (e0 + PER <= E) {
            if (is64) {
                const long long* pr = (const long long*)edge + e0;
                const long long* pc = (const long long*)edge + E + e0;
#pragma unroll
                for (int j = 0; j < PER; j += 2) {
                    longlong2 vr = *(const longlong2*)(pr + j);
                    longlong2 vc = *(const longlong2*)(pc + j);
                    rr[j] = (int)vr.x; rr[j + 1] = (int)vr.y;
                    cc[j] = (int)vc.x; cc[j + 1] = (int)vc.y;
                }
            } else {
                const int* pr = (const int*)edge + e0;
                const int* pc = (const int*)edge + E + e0;
#pragma unroll
                for (int j = 0; j < PER; j += 4) {
                    int4 vr = *(const int4*)(pr + j);
                    int4 vc = *(const int4*)(pc + j);
                    rr[j] = vr.x; rr[j + 1] = vr.y; rr[j + 2] = vr.z; rr[j + 3] = vr.w;
                    cc[j] = vc.x; cc[j + 1] = vc.y; cc[j + 2] = vc.z; cc[j + 3] = vc.w;
                }
            }
#pragma unroll
            for (int j = 0; j < PER; ++j) {
                int b = rr[j] / rpb;
                bkt[j] = b;
                enc[j] = ((unsigned)(rr[j] - b * rpb) << 16) | (unsigned)(cc[j] & 0xFFFF);
                rank[j] = atomicAdd(&lcnt[b], 1);
            }
        } else {
#pragma unroll
            for (int j = 0; j < PER; ++j) {
                long long e = e0 + j;
                if (e < E) {
                    int r = g_idx(edge, e, is64);
                    int c = g_idx(edge, (long long)E + e, is64);
                    int b = r / rpb;
                    bkt[j] = b;
                    enc[j] = ((unsigned)(r - b * rpb) << 16) | (unsigned)(c & 0xFFFF);
                    rank[j] = atomicAdd(&lcnt[b], 1);
                } else bkt[j] = -1;
            }
        }
        __syncthreads();
        if (t < NBKT) lbase[t] = atomicAdd(&bucketcnt[t], lcnt[t]);
        __syncthreads();
#pragma unroll
        for (int j = 0; j < PER; ++j) {
            if (bkt[j] >= 0) {
                int pos = lbase[bkt[j]] + rank[j];
                if (pos < BCAP)
                    bucketbuf[(size_t)bkt[j] * BCAP + pos] = enc[j];
            }
        }
    }
}

// -------- tiny prefix over bucket counts (removes per-block serial scan in bsort) ----
__global__ __launch_bounds__(NBKT) void k_pfx(const int* __restrict__ bucketcnt,
                                              int* __restrict__ bktbase) {
    __shared__ int s[NBKT];
    int t = threadIdx.x;
    int v = bucketcnt[t];
    if (v > BCAP) v = BCAP;
    s[t] = v;
    __syncthreads();
    for (int off = 1; off < NBKT; off <<= 1) {
        int x = (t >= off) ? s[t - off] : 0;
        __syncthreads();
        s[t] += x;
        __syncthreads();
    }
    bktbase[t] = s[t] - v;
    if (t == NBKT - 1) bktbase[NBKT] = s[t];
}

// -------- phase B: block b owns bucket b == rows [b*rpb, b*rpb+rpb) --------
__global__ __launch_bounds__(512) void k_bsort(
        const unsigned* __restrict__ bucketbuf, const int* __restrict__ bucketcnt,
        const int* __restrict__ bktbase,
        int* __restrict__ rowptr, float* __restrict__ dinv, float* __restrict__ di2,
        float* __restrict__ rdinv, unsigned short* __restrict__ cols16, int N, int rpb) {
    __shared__ int hist[512];
    int b = blockIdx.x;
    int t = threadIdx.x;
    int base = bktbase[b];
    int cnt = bucketcnt[b];
    if (cnt > BCAP) cnt = BCAP;
    int r0 = b * rpb;
    int rows = N - r0;
    if (rows > rpb) rows = rpb;
    if (rows < 0) rows = 0;

    hist[t] = 0;
    __syncthreads();
    const unsigned* buf = bucketbuf + (size_t)b * BCAP;
    for (int i = t; i < cnt; i += 512) atomicAdd(&hist[buf[i] >> 16], 1);
    __syncthreads();
    int v = hist[t];
    __syncthreads();
    for (int off = 1; off < 512; off <<= 1) {
        int x = (t >= off) ? hist[t - off] : 0;
        __syncthreads();
        hist[t] += x;
        __syncthreads();
    }
    int excl = hist[t] - v;
    if (t < rows) {
        int r = r0 + t;
        rowptr[r] = base + excl;
        float fd = (float)v;
        float dv = (v > 0) ? rsqrtf(fd) : 0.0f;
        dinv[r] = dv;
        di2[r] = dv * dv;
        rdinv[r] = (v > 0) ? sqrtf(fd) : 0.0f;
    }
    if (b == NBKT - 1 && t == 0) rowptr[N] = bktbase[NBKT];
    __syncthreads();
    hist[t] = base + excl;  // global cursor per owned row
    __syncthreads();
    for (int i = t; i < cnt; i += 512) {
        unsigned u = buf[i];
        int pos = atomicAdd(&hist[u >> 16], 1);
        cols16[pos] = (unsigned short)(u & 0xFFFF);
    }
}

// -------- init + prep fused: h0/g0 (slice-major), W1T transpose, biases, n_id marking ----
__global__ void k_initprep(const void* emb, const float* __restrict__ dinv,
                           unsigned* __restrict__ h0, unsigned* __restrict__ g0,
                           unsigned* __restrict__ g1, unsigned* __restrict__ g2,
                           int n2, int SST,
                           const void* w1, const void* b1, const void* w2, const void* b2,
                           unsigned short* __restrict__ w1t, float* __restrict__ b1f,
                           float* __restrict__ w2f, float* __restrict__ b2f,
                           const void* n_id, int nids, unsigned char* __restrict__ mark) {
    __shared__ int sf32, sid;
    int t = threadIdx.x;
    if (t < 64) {
        const unsigned short* h = (const unsigned short*)emb;
        int ex = (h[2 * t] >> 7) & 0xFF;
        unsigned long long mP = __ballot(ex >= 0x6C && ex <= 0x7F);
        const unsigned* nw = (const unsigned*)n_id;
        int predB = (t < 32) ? (nw[2 * t + 1] == 0u) : 1;
        unsigned long long mB = __ballot(predB);
        if (t == 0) {
            sf32 = (__popcll(mP) < 32) ? 1 : 0;
            sid = (mB == ~0ull) ? 1 : 0;
        }
    }
    __syncthreads();
    int f32 = sf32, id64 = sid;
    int i = blockIdx.x * blockDim.x + t;
    if (i < n2) {
        float lo = g_flt(emb, 2LL * i, f32);
        float hi = g_flt(emb, 2LL * i + 1, f32);
        int n = i >> 6, w = i & 63;
        size_t o = (size_t)(w >> 5) * SST + (size_t)n * 32 + (w & 31);
        h0[o] = packbf(lo, hi);
        float dv = dinv[n];
        g0[o] = packbf(lo * dv, hi * dv);
    }
    if (i < nids) mark[g_idx(n_id, i, id64)] = 1;  // rows needed by the head
    if (i < 256 * 128) {
        int k = i >> 7, n = i & 127;
        w1t[n * 256 + k] = f2bf(g_flt(w1, i, f32));
    }
    if (i < 128) {
        b1f[i] = g_flt(b1, i, f32);
        w2f[i] = g_flt(w2, i, f32);
    }
    if (i == 0) b2f[0] = g_flt(b2, 0, f32);
    if (i < 64) {  // zero sentinel row N (both slices) of g0,g1,g2
        int s = i >> 5, w = i & 31;
        size_t o = (size_t)s * SST + (size_t)(n2 >> 6) * 32 + w;
        g0[o] = 0u; g1[o] = 0u; g2[o] = 0u;
    }
}

// -------- compact marked nodes: block-aggregated, intra-block node order preserved ----
__global__ __launch_bounds__(256) void k_compact(const unsigned char* __restrict__ mark, int N,
                                                 int* __restrict__ cnt, int* __restrict__ clist) {
    __shared__ int wbase[4];
    int n = blockIdx.x * blockDim.x + threadIdx.x;
    int m = (n < N) ? (mark[n] ? 1 : 0) : 0;
    int lane = threadIdx.x & 63, wave = threadIdx.x >> 6;
    unsigned long long bal = __ballot(m);
    int rank = __popcll(bal & ((1ull << lane) - 1ull));
    if (lane == 0) wbase[wave] = __popcll(bal);
    __syncthreads();
    if (threadIdx.x == 0) {
        int tot = wbase[0] + wbase[1] + wbase[2] + wbase[3];
        int b0 = atomicAdd(cnt, tot);
        int acc = b0;
#pragma unroll
        for (int w = 0; w < 4; ++w) { int c = wbase[w]; wbase[w] = acc; acc += c; }
    }
    __syncthreads();
    if (m) clist[wbase[wave] + rank] = n;
}

// -------- propagation (2-slice, octet-per-node-slice, 8 neighbors/trip) --------
// slice pinned to an XCD half: slice = (blockIdx&7)>>2.
__global__ void k_layer(const int* __restrict__ rowptr, const unsigned short* __restrict__ cols16,
                        const uint4* __restrict__ gin, uint4* __restrict__ gout,
                        const float* __restrict__ di2, int N, int SSTU4) {
    int b = blockIdx.x;
    int slice = (b >> 2) & 1;
    int tile = ((b >> 3) << 2) | (b & 3);
    int node = tile * 32 + (threadIdx.x >> 3);
    if (node >= N) return;
    int l8 = threadIdx.x & 7;
    const uint4* gs = gin + (size_t)slice * SSTU4;
    int p = rowptr[node];
    int end = rowptr[node + 1];
    float a0 = 0.f, a1 = 0.f, a2 = 0.f, a3 = 0.f;
    float a4 = 0.f, a5 = 0.f, a6 = 0.f, a7 = 0.f;
    for (int base = p; base < end; base += 8) {
        int c[8];
#pragma unroll
        for (int j = 0; j < 8; ++j) {
            int idx = base + j;
            int cv = cols16[idx];
            c[j] = (idx < end) ? cv : N;
        }
#pragma unroll
        for (int j = 0; j < 8; ++j) {
            uint4 v = gs[(size_t)c[j] * 8 + l8];
            a0 += bflo(v.x); a1 += bfhi(v.x);
            a2 += bflo(v.y); a3 += bfhi(v.y);
            a4 += bflo(v.z); a5 += bfhi(v.z);
            a6 += bflo(v.w); a7 += bfhi(v.w);
        }
    }
    float s = di2[node];
    uint4 o;
    o.x = packbf(a0 * s, a1 * s);
    o.y = packbf(a2 * s, a3 * s);
    o.z = packbf(a4 * s, a5 * s);
    o.w = packbf(a6 * s, a7 * s);
    gout[(size_t)slice * SSTU4 + (size_t)node * 8 + l8] = o;
}

// -------- layer 3: dense waves over compacted list (8-unroll); fused finalize --------
__global__ void k_layer3(const int* __restrict__ rowptr, const unsigned short* __restrict__ cols16,
                         const uint4* __restrict__ gin /*g2*/, const uint4* __restrict__ h0,
                         const uint4* __restrict__ g1, uint4* __restrict__ fin,
                         const float* __restrict__ di2, const float* __restrict__ rdinv,
                         const int* __restrict__ cnt, const int* __restrict__ clist,
                         int N, int SSTU4, int TILES_PER) {
    int b = blockIdx.x;
    int slice = (b >> 2) & 1;
    int tile = ((b >> 3) << 2) | (b & 3);
    int nsub = threadIdx.x >> 3;
    int l8 = threadIdx.x & 7;
    int cntv = *cnt;
    size_t sb = (size_t)slice * SSTU4;
    const uint4* gs = gin + sb;
    for (int tl = tile; tl * 32 < cntv; tl += TILES_PER) {
        int li = tl * 32 + nsub;
        if (li < cntv) {
            int node = clist[li];
            int p = rowptr[node], end = rowptr[node + 1];
            float a0 = 0.f, a1 = 0.f, a2 = 0.f, a3 = 0.f;
            float a4 = 0.f, a5 = 0.f, a6 = 0.f, a7 = 0.f;
            for (int base = p; base < end; base += 8) {
                int c[8];
#pragma unroll
                for (int j = 0; j < 8; ++j) {
                    int idx = base + j;
                    int cv = cols16[idx];
                    c[j] = (idx < end) ? cv : N;
                }
#pragma unroll
                for (int j = 0; j < 8; ++j) {
                    uint4 v = gs[(size_t)c[j] * 8 + l8];
                    a0 += bflo(v.x); a1 += bfhi(v.x);
                    a2 += bflo(v.y); a3 += bfhi(v.y);
                    a4 += bflo(v.z); a5 += bfhi(v.z);
                    a6 += bflo(v.w); a7 += bfhi(v.w);
                }
            }
            float s = di2[node];
            float rd = rdinv[node];
            size_t ro = (size_t)node * 8 + l8;
            uint4 x0 = h0[sb + ro];
            uint4 x1 = g1[sb + ro];
            uint4 x2 = gs[ro];
            uint4 o;
            o.x = packbf(0.25f * (bflo(x0.x) + rd * (bflo(x1.x) + bflo(x2.x) + s * a0)),
                         0.25f * (bfhi(x0.x) + rd * (bfhi(x1.x) + bfhi(x2.x) + s * a1)));
            o.y = packbf(0.25f * (bflo(x0.y) + rd * (bflo(x1.y) + bflo(x2.y) + s * a2)),
                         0.25f * (bfhi(x0.y) + rd * (bfhi(x1.y) + bfhi(x2.y) + s * a3)));
            o.z = packbf(0.25f * (bflo(x0.z) + rd * (bflo(x1.z) + bflo(x2.z) + s * a4)),
                         0.25f * (bfhi(x0.z) + rd * (bfhi(x1.z) + bfhi(x2.z) + s * a5)));
            o.w = packbf(0.25f * (bflo(x0.w) + rd * (bflo(x1.w) + bflo(x2.w) + s * a6)),
                         0.25f * (bfhi(x0.w) + rd * (bfhi(x1.w) + bfhi(x2.w) + s * a7)));
            fin[(size_t)node * 16 + slice * 8 + l8] = o;
        }
    }
}

// -------- MFMA head (fin node-major, uint4 staging; id64 detected inline) --------
__global__ void k_head(const uint4* __restrict__ fin, const void* n_id,
                       const unsigned short* __restrict__ w1t,
                       const float* __restrict__ b1f, const float* __restrict__ w2f,
                       const float* __restrict__ b2f,
                       float* __restrict__ out, int B, int NEG) {
    __shared__ unsigned short z[64][264];
    __shared__ int sid;
    int t = threadIdx.x;
    if (t < 64) {
        const unsigned* nw = (const unsigned*)n_id;
        int predB = (t < 32) ? (nw[2 * t + 1] == 0u) : 1;
        unsigned long long mB = __ballot(predB);
        if (t == 0) sid = (mB == ~0ull) ? 1 : 0;
    }
    __syncthreads();
    int id64 = sid;
    int mbase = blockIdx.x * 64;

#pragma unroll
    for (int i = 0; i < 8; ++i) {
        int flat = i * 256 + t;        // 0..2047
        int m = flat >> 5;             // 0..63
        int q = flat & 31;             // uint4 slot within z row
        int gm = mbase + m;
        int r;
        if (gm < B) {
            r = (q < 16) ? g_idx(n_id, gm, id64) : g_idx(n_id, B + gm, id64);
        } else {
            int j = gm - B;
            r = (q < 16) ? g_idx(n_id, j / NEG, id64) : g_idx(n_id, 2 * B + j, id64);
        }
        uint4 v = fin[(size_t)r * 16 + (q & 15)];
        *(uint4*)((char*)&z[m][0] + q * 16) = v;
    }
    __syncthreads();

    int wave = t >> 6, lane = t & 63;
    int quad = lane >> 4, l16 = lane & 15;

    floatx4 acc[8] = {};
    bf16x8 a[8];
    const unsigned short* zrow = &z[wave * 16 + l16][0];
#pragma unroll
    for (int ks = 0; ks < 8; ++ks)
        a[ks] = *(const bf16x8*)(zrow + ks * 32 + quad * 8);

#pragma unroll
    for (int ks = 0; ks < 8; ++ks) {
#pragma unroll
        for (int nt = 0; nt < 8; ++nt) {
            bf16x8 b = *(const bf16x8*)(w1t + (nt * 16 + l16) * 256 + ks * 32 + quad * 8);
            acc[nt] = __builtin_amdgcn_mfma_f32_16x16x32_bf16(a[ks], b, acc[nt], 0, 0, 0);
        }
    }

    float s0 = 0.f, s1 = 0.f, s2 = 0.f, s3 = 0.f;
#pragma unroll
    for (int nt = 0; nt < 8; ++nt) {
        int col = nt * 16 + l16;
        float bb = b1f[col], ww = w2f[col];
        float v0 = acc[nt][0] + bb; v0 = (v0 > 0.f) ? v0 : 0.2f * v0; s0 += v0 * ww;
        float v1 = acc[nt][1] + bb; v1 = (v1 > 0.f) ? v1 : 0.2f * v1; s1 += v1 * ww;
        float v2 = acc[nt][2] + bb; v2 = (v2 > 0.f) ? v2 : 0.2f * v2; s2 += v2 * ww;
        float v3 = acc[nt][3] + bb; v3 = (v3 > 0.f) ? v3 : 0.2f * v3; s3 += v3 * ww;
    }
#pragma unroll
    for (int off = 1; off <= 8; off <<= 1) {
        s0 += __shfl_xor(s0, off, 64);
        s1 += __shfl_xor(s1, off, 64);
        s2 += __shfl_xor(s2, off, 64);
        s3 += __shfl_xor(s3, off, 64);
    }
    if (l16 == 0) {
        int rowbase = mbase + wave * 16 + quad * 4;
        float bb2 = b2f[0];
        out[rowbase + 0] = s0 + bb2;
        out[rowbase + 1] = s1 + bb2;
        out[rowbase + 2] = s2 + bb2;
        out[rowbase + 3] = s3 + bb2;
    }
}

extern "C" void kernel_launch(void* const* d_in, const int* in_sizes, int n_in,
                              void* d_out, int out_size, void* d_ws, size_t ws_size,
                              hipStream_t stream) {
    const void* edge_index = d_in[1];
    const void* n_id       = d_in[3];
    const void* id_embed   = d_in[5];
    const void* w1 = d_in[6];
    const void* b1 = d_in[7];
    const void* w2 = d_in[8];
    const void* b2 = d_in[9];
    float* out = (float*)d_out;

    const int E  = in_sizes[1] / 2;
    const int N  = in_sizes[5] / C;
    const int NEG = 5;
    const int B  = in_sizes[3] / (2 + NEG);
    const int nids = (2 + NEG) * B;      // 28672
    const int n_out_rows = B + B * NEG;  // 24576
    const int SST = (N + 1) * 32;        // slice stride in u32 (2 slices)
    const int SSTU4 = (N + 1) * 8;       // slice stride in uint4
    const int NB = 2 * SST;              // u32 per slice-major buffer
    const int rpb = (N + NBKT - 1) / NBKT;  // 196 (<=512, fits 16-bit row-in-bucket)

    size_t off = 0;
    auto alloc = [&](size_t nf) {
        char* p = (char*)d_ws + off * 4;
        off += (nf + 255) & ~(size_t)255;
        return p;
    };
    int*   bucketcnt = (int*)alloc(NBKT);       // NBKT=256 ints; [+pad] then mark follows
    int*   ccnt      = (int*)alloc(8);          // compact counter (own padded slot, zeroed)
    unsigned char* mark = (unsigned char*)alloc((N + 3) / 4);  // contiguous: still in memset span
    int*   bktbase   = (int*)alloc(NBKT + 1);
    int*   clist     = (int*)alloc(N);
    float* dinv      = (float*)alloc(N + 1);
    float* di2       = (float*)alloc(N);
    float* rdinv     = (float*)alloc(N);
    int*   rowptr    = (int*)alloc(N + 1);
    unsigned short* cols16 = (unsigned short*)alloc(((size_t)E + 16 + 1) / 2);
    unsigned* bucketbuf = (unsigned*)alloc((size_t)NBKT * BCAP);
    unsigned* h0     = (unsigned*)alloc(NB);
    unsigned* g0     = (unsigned*)alloc(NB);
    unsigned* g1     = (unsigned*)alloc(NB);
    unsigned* g2     = (unsigned*)alloc(NB);
    unsigned* fin    = (unsigned*)alloc((size_t)N * 64);
    unsigned short* w1t = (unsigned short*)alloc(256 * 128 / 2);
    float* b1f       = (float*)alloc(C);
    float* w2f       = (float*)alloc(C);
    float* b2f       = (float*)alloc(8);

    const int BS = 256;
    // one memset covers bucketcnt + ccnt + mark (contiguous regions)
    size_t zlen = (size_t)((char*)bktbase - (char*)bucketcnt);
    hipMemsetAsync(bucketcnt, 0, zlen, stream);

    const int gridA = (E + BS * 8 - 1) / (BS * 8);
    k_bucketA<<<gridA, BS, 0, stream>>>(edge_index, E, rpb, bucketbuf, bucketcnt);
    k_pfx<<<1, NBKT, 0, stream>>>(bucketcnt, bktbase);
    k_bsort<<<NBKT, 512, 0, stream>>>(bucketbuf, bucketcnt, bktbase, rowptr, dinv, di2,
                                      rdinv, cols16, N, rpb);
    k_initprep<<<(N * 64 + BS - 1) / BS, BS, 0, stream>>>(
        id_embed, dinv, h0, g0, g1, g2, N * 64, SST, w1, b1, w2, b2,
        w1t, b1f, w2f, b2f, n_id, nids, mark);
    k_compact<<<(N + BS - 1) / BS, BS, 0, stream>>>(mark, N, ccnt, clist);

    // layers: slice = (blockIdx&7)>>2, tile = ((b>>3)<<2)|(b&3); grid multiple of 8
    const int tiles = (N + 31) / 32;
    const int layer_grid = 8 * ((tiles + 3) / 4);
    const int TILES_PER = 4 * ((tiles + 3) / 4);
    k_layer<<<layer_grid, BS, 0, stream>>>(rowptr, cols16, (const uint4*)g0, (uint4*)g1,
                                           di2, N, SSTU4);
    k_layer<<<layer_grid, BS, 0, stream>>>(rowptr, cols16, (const uint4*)g1, (uint4*)g2,
                                           di2, N, SSTU4);
    k_layer3<<<layer_grid, BS, 0, stream>>>(rowptr, cols16, (const uint4*)g2, (const uint4*)h0,
                                            (const uint4*)g1, (uint4*)fin, di2, rdinv,
                                            ccnt, clist, N, SSTU4, TILES_PER);

    k_head<<<n_out_rows / 64, BS, 0, stream>>>((const uint4*)fin, n_id, w1t, b1f, w2f, b2f,
                                               out, B, NEG);
}